// Round 9
// baseline (66.507 us; speedup 1.0000x reference)
//
#include <hip/hip_runtime.h>

static constexpr int S_SYS   = 8;
static constexpr int E_PAIRS = 1000000;
static constexpr int N_A     = 20000;
static constexpr int NBINS   = 16;
static constexpr int BPS     = 32;                 // blocks per system; 256 total = 1/CU
static constexpr int BLK     = 1024;
static constexpr int UNR     = 4;
static constexpr int A_SLICE = N_A / BPS;          // 625 atoms per block's kde slice
static constexpr float SCALE   = 4194304.0f;       // 2^22
static constexpr float INV_SCL = 1.0f / 4194304.0f;
static constexpr unsigned ONE_FX = 4194304u;
static constexpr float QLO = 19.36f;               // 4.4^2  (z==1 below)
static constexpr float QHI = 30.25f;               // 5.5^2  (z==0 above)
static constexpr float INV11 = 1.0f / 1.1f;
static constexpr size_t PARTIAL_B = (size_t)S_SYS * BPS * N_A * 4;  // 20,480,000 B

// Fused: coord (LDS u32 fixed-point, shell-skip) -> per-system release/acquire
// barrier -> in-kernel KDE on a 625-atom slice. 256 blocks, 1/CU, co-resident.
__global__ __launch_bounds__(BLK, 4) void coord_fused(
    const float* __restrict__ vec, const int* __restrict__ atom,
    unsigned* __restrict__ partial, unsigned* __restrict__ cnt,
    float* __restrict__ out)
{
    __shared__ __align__(16) unsigned lc[N_A];        // 80 KB
    for (int i = threadIdx.x; i < N_A; i += BLK) lc[i] = 0u;
    __syncthreads();

    const int s = blockIdx.y;
    const int b = blockIdx.x;
    const int Q = E_PAIRS / 4;
    const float4* vb = reinterpret_cast<const float4*>(vec) + (size_t)s * Q * 3;
    const int4*   ib = reinterpret_cast<const int4*>(atom) + (size_t)s * Q;

    // ---- phase 1: pair accumulation ----
    const int W = BPS * BLK;                          // 32768
    for (int t = b * BLK + threadIdx.x; t < Q; t += W * UNR) {
        float4 A[UNR], B[UNR], C[UNR];
        int4   id[UNR];
        bool   ok[UNR];
        #pragma unroll
        for (int u = 0; u < UNR; ++u) {
            int tq = t + u * W;
            ok[u] = (tq < Q);
            if (ok[u]) {
                A[u] = vb[3 * tq]; B[u] = vb[3 * tq + 1]; C[u] = vb[3 * tq + 2];
                id[u] = ib[tq];
            }
        }
        #pragma unroll
        for (int u = 0; u < UNR; ++u) {
            if (!ok[u]) continue;
            float px[4] = {A[u].x, A[u].w, B[u].z, C[u].y};
            float py[4] = {A[u].y, B[u].x, B[u].w, C[u].z};
            float pz[4] = {A[u].z, B[u].y, C[u].x, C[u].w};
            int ids[4]  = {id[u].x, id[u].y, id[u].z, id[u].w};
            #pragma unroll
            for (int j = 0; j < 4; ++j) {
                float q = px[j]*px[j] + py[j]*py[j] + pz[j]*pz[j];
                if (q < QLO) {
                    atomicAdd(&lc[ids[j]], ONE_FX);           // z == 1
                } else if (q < QHI) {
                    float d = sqrtf(q);
                    float y = (d - 4.4f) * INV11;
                    float uu = y - 1.0f;
                    float z = uu * uu * (1.0f + 2.0f * y);
                    unsigned fx = __float2uint_rn(z * SCALE);
                    if (fx) atomicAdd(&lc[ids[j]], fx);       // ds_add_u32
                }
            }
        }
    }
    __syncthreads();                                  // drain ds_adds

    // ---- phase 2: publish partial ----
    uint4* po = reinterpret_cast<uint4*>(partial + ((size_t)s * BPS + b) * N_A);
    const uint4* ls = reinterpret_cast<const uint4*>(lc);
    for (int i = threadIdx.x; i < N_A / 4; i += BLK) po[i] = ls[i];

    if (b == 0) {                                     // zero this system's out bins
        if (threadIdx.x < NBINS) out[s * NBINS + threadIdx.x] = 0.0f;
    }
    __syncthreads();                                  // all stores issued+drained (vmcnt(0))

    if (threadIdx.x == 0)
        __hip_atomic_fetch_add(&cnt[s], 1u, __ATOMIC_RELEASE, __HIP_MEMORY_SCOPE_AGENT);

    // ---- phase 3: wait for this system's 32 partials ----
    if (threadIdx.x == 0) {
        while (__hip_atomic_load(&cnt[s], __ATOMIC_RELAXED, __HIP_MEMORY_SCOPE_AGENT) < (unsigned)BPS)
            __builtin_amdgcn_s_sleep(1);
        (void)__hip_atomic_load(&cnt[s], __ATOMIC_ACQUIRE, __HIP_MEMORY_SCOPE_AGENT);
    }
    __syncthreads();

    // ---- phase 4: KDE on atoms [b*625, (b+1)*625) of system s ----
    const int a0 = b * A_SLICE;
    const int t  = threadIdx.x;
    bool valid = (t < A_SLICE);

    unsigned acc = 0u;
    if (valid) {
        const unsigned* p = partial + (size_t)s * BPS * N_A + a0 + t;
        #pragma unroll 8
        for (int bb = 0; bb < BPS; ++bb) acc += p[(size_t)bb * N_A];
    }
    float c = (float)acc * INV_SCL;

    float vals[NBINS];
    #pragma unroll
    for (int k = 0; k < NBINS; ++k) {
        float d = c - (float)k;
        vals[k] = valid ? expf(-2.0f * d * d) : 0.0f;  // 0.5/SIGMA2 == 2
    }
    #pragma unroll
    for (int k = 0; k < NBINS; ++k) {
        #pragma unroll
        for (int off = 32; off > 0; off >>= 1)
            vals[k] += __shfl_down(vals[k], off, 64);
    }

    float* sbin = reinterpret_cast<float*>(lc);        // reuse LDS: [16 waves][16 bins]
    int wave = threadIdx.x >> 6, lane = threadIdx.x & 63;
    if (lane == 0) {
        #pragma unroll
        for (int k = 0; k < NBINS; ++k) sbin[wave * NBINS + k] = vals[k];
    }
    __syncthreads();
    if (threadIdx.x < NBINS) {
        float v = 0.0f;
        #pragma unroll
        for (int w = 0; w < BLK / 64; ++w) v += sbin[w * NBINS + threadIdx.x];
        unsafeAtomicAdd(&out[s * NBINS + threadIdx.x], v);
    }
}

// ---------------- Fallback path (ws too small): global-atomic scatter --------
__global__ __launch_bounds__(256) void coord_scatter(
    const float* __restrict__ vec, const int* __restrict__ atom,
    float* __restrict__ coords)
{
    const int P4 = S_SYS * E_PAIRS / 4;
    int stride = gridDim.x * blockDim.x;
    for (int t = blockIdx.x * blockDim.x + threadIdx.x; t < P4; t += stride) {
        const float4* v4 = reinterpret_cast<const float4*>(vec) + 3ull * (unsigned)t;
        float4 A = v4[0], B = v4[1], C = v4[2];
        int4 id = reinterpret_cast<const int4*>(atom)[t];
        int s = (t * 4) / E_PAIRS;
        float* cs = coords + s * N_A;
        float px[4] = {A.x, A.w, B.z, C.y};
        float py[4] = {A.y, B.x, B.w, C.z};
        float pz[4] = {A.z, B.y, C.x, C.w};
        int ids[4]  = {id.x, id.y, id.z, id.w};
        #pragma unroll
        for (int j = 0; j < 4; ++j) {
            float d = sqrtf(px[j]*px[j] + py[j]*py[j] + pz[j]*pz[j]);
            float y = (d - 4.4f) / 1.1f;
            float z;
            if (y <= 0.0f)      z = 1.0f;
            else if (y >= 1.0f) z = 0.0f;
            else { float u = y - 1.0f; z = u * u * (1.0f + 2.0f * y); }
            if (z != 0.0f) unsafeAtomicAdd(&cs[ids[j]], z);
        }
    }
}

__global__ __launch_bounds__(256) void kde_reduce_f32(
    const float* __restrict__ coords, float* __restrict__ out)
{
    int s = blockIdx.y;
    int a = blockIdx.x * 256 + threadIdx.x;
    bool valid = (a < N_A);
    float c = valid ? coords[(size_t)s * N_A + a] : 0.0f;

    float vals[NBINS];
    #pragma unroll
    for (int k = 0; k < NBINS; ++k) {
        float d = c - (float)k;
        vals[k] = valid ? expf(-2.0f * d * d) : 0.0f;
    }
    #pragma unroll
    for (int k = 0; k < NBINS; ++k) {
        #pragma unroll
        for (int off = 32; off > 0; off >>= 1)
            vals[k] += __shfl_down(vals[k], off, 64);
    }
    __shared__ float sbin[4][NBINS];
    int wave = threadIdx.x >> 6;
    int lane = threadIdx.x & 63;
    if (lane == 0) {
        #pragma unroll
        for (int k = 0; k < NBINS; ++k) sbin[wave][k] = vals[k];
    }
    __syncthreads();
    if (threadIdx.x < NBINS) {
        float v = sbin[0][threadIdx.x] + sbin[1][threadIdx.x]
                + sbin[2][threadIdx.x] + sbin[3][threadIdx.x];
        unsafeAtomicAdd(&out[s * NBINS + threadIdx.x], v);
    }
}

extern "C" void kernel_launch(void* const* d_in, const int* in_sizes, int n_in,
                              void* d_out, int out_size, void* d_ws, size_t ws_size,
                              hipStream_t stream) {
    const float* vec  = (const float*)d_in[0];   // [S,E,3] f32
    const int*   atom = (const int*)d_in[1];     // [S,E] i32
    float* out = (float*)d_out;                  // [S,16] f32

    if (ws_size >= PARTIAL_B + 64) {
        unsigned* ws  = (unsigned*)d_ws;
        unsigned* cnt = (unsigned*)((char*)d_ws + PARTIAL_B);
        hipMemsetAsync(cnt, 0, S_SYS * sizeof(unsigned), stream);  // barrier counters
        dim3 g1(BPS, S_SYS);                      // 256 blocks, 1/CU, co-resident
        coord_fused<<<g1, BLK, 0, stream>>>(vec, atom, ws, cnt, out);
    } else {
        float* ws = (float*)d_ws;
        hipMemsetAsync(out, 0, (size_t)S_SYS * NBINS * sizeof(float), stream);
        hipMemsetAsync(ws, 0, (size_t)S_SYS * N_A * sizeof(float), stream);
        coord_scatter<<<2048, 256, 0, stream>>>(vec, atom, ws);
        dim3 g2((N_A + 255) / 256, S_SYS);
        kde_reduce_f32<<<g2, 256, 0, stream>>>(ws, out);
    }
}

// Round 10
// 40.902 us; speedup vs baseline: 1.6260x; 1.6260x over previous
//
#include <hip/hip_runtime.h>

static constexpr int S_SYS   = 8;
static constexpr int E_PAIRS = 1000000;
static constexpr int N_A     = 20000;
static constexpr int NBINS   = 16;
static constexpr int BPS     = 32;                 // 256 blocks = 1/CU
static constexpr int BLK     = 1024;
static constexpr int UNR     = 2;                  // quad-groups in flight
static constexpr float SCALE   = 4194304.0f;       // 2^22
static constexpr float INV_SCL = 1.0f / 4194304.0f;
static constexpr float INV11 = 1.0f / 1.1f;

// Kernel 1: LDS-privatized u32 fixed-point coords, fire-and-forget ds_add_u32.
// Branchless switching: y clamped to [0,1] via fmin/fmax (v_med3-style), the
// polynomial is exact at both clamp ends, so every pair issues exactly ONE
// ds_add (zero-adds harmless) -- no divergent dual-atomic paths.
__global__ __launch_bounds__(BLK, 4) void coord_lds_u32(
    const float* __restrict__ vec, const int* __restrict__ atom,
    unsigned* __restrict__ partial)
{
    __shared__ __align__(16) unsigned lc[N_A];        // 80 KB
    for (int i = threadIdx.x; i < N_A; i += BLK) lc[i] = 0u;
    __syncthreads();

    const int s = blockIdx.y;
    const int Q = E_PAIRS / 4;                        // 250,000 quad-groups/system
    const float4* vb = reinterpret_cast<const float4*>(vec) + (size_t)s * Q * 3;
    const int4*   ib = reinterpret_cast<const int4*>(atom) + (size_t)s * Q;

    const int W = BPS * BLK;                          // 32768
    for (int t = blockIdx.x * BLK + threadIdx.x; t < Q; t += W * UNR) {
        float4 A[UNR], B[UNR], C[UNR];
        int4   id[UNR];
        bool   ok[UNR];
        #pragma unroll
        for (int u = 0; u < UNR; ++u) {
            int tq = t + u * W;
            ok[u] = (tq < Q);
            if (ok[u]) {
                A[u] = vb[3 * tq]; B[u] = vb[3 * tq + 1]; C[u] = vb[3 * tq + 2];
                id[u] = ib[tq];
            }
        }
        #pragma unroll
        for (int u = 0; u < UNR; ++u) {
            if (!ok[u]) continue;
            float px[4] = {A[u].x, A[u].w, B[u].z, C[u].y};
            float py[4] = {A[u].y, B[u].x, B[u].w, C[u].z};
            float pz[4] = {A[u].z, B[u].y, C[u].x, C[u].w};
            int ids[4]  = {id[u].x, id[u].y, id[u].z, id[u].w};
            #pragma unroll
            for (int j = 0; j < 4; ++j) {
                float q = px[j]*px[j] + py[j]*py[j] + pz[j]*pz[j];
                float d = sqrtf(q);
                float y = (d - 4.4f) * INV11;         // (d - R1) / (R0 - R1)
                y = fminf(fmaxf(y, 0.0f), 1.0f);      // med3 clamp; poly exact at ends
                float uu = y - 1.0f;
                float z = uu * uu * (1.0f + 2.0f * y);
                atomicAdd(&lc[ids[j]], __float2uint_rn(z * SCALE));  // ds_add_u32
            }
        }
    }
    __syncthreads();

    uint4* po = reinterpret_cast<uint4*>(partial + ((size_t)s * BPS + blockIdx.x) * N_A);
    const uint4* ls = reinterpret_cast<const uint4*>(lc);
    for (int i = threadIdx.x; i < N_A / 4; i += BLK) po[i] = ls[i];
}

// Kernel 2 (fast path): exact u32 sum of partials -> float coord -> KDE.
__global__ __launch_bounds__(256) void kde_reduce_u32(
    const unsigned* __restrict__ partial, float* __restrict__ out)
{
    int s = blockIdx.y;
    int a = blockIdx.x * 256 + threadIdx.x;
    bool valid = (a < N_A);

    unsigned acc = 0u;
    if (valid) {
        const unsigned* p = partial + (size_t)s * BPS * N_A + a;
        #pragma unroll 8
        for (int b = 0; b < BPS; ++b) acc += p[(size_t)b * N_A];
    }
    float c = (float)acc * INV_SCL;

    float vals[NBINS];
    #pragma unroll
    for (int k = 0; k < NBINS; ++k) {
        float d = c - (float)k;
        vals[k] = valid ? expf(-2.0f * d * d) : 0.0f;  // 0.5/SIGMA2 == 2
    }

    #pragma unroll
    for (int k = 0; k < NBINS; ++k) {
        #pragma unroll
        for (int off = 32; off > 0; off >>= 1)
            vals[k] += __shfl_down(vals[k], off, 64);
    }

    __shared__ float sbin[4][NBINS];
    int wave = threadIdx.x >> 6;
    int lane = threadIdx.x & 63;
    if (lane == 0) {
        #pragma unroll
        for (int k = 0; k < NBINS; ++k) sbin[wave][k] = vals[k];
    }
    __syncthreads();
    if (threadIdx.x < NBINS) {
        float v = sbin[0][threadIdx.x] + sbin[1][threadIdx.x]
                + sbin[2][threadIdx.x] + sbin[3][threadIdx.x];
        unsafeAtomicAdd(&out[s * NBINS + threadIdx.x], v);
    }
}

// ---------------- Fallback path (ws too small): global-atomic scatter --------
__global__ __launch_bounds__(256) void coord_scatter(
    const float* __restrict__ vec, const int* __restrict__ atom,
    float* __restrict__ coords)
{
    const int P4 = S_SYS * E_PAIRS / 4;
    int stride = gridDim.x * blockDim.x;
    for (int t = blockIdx.x * blockDim.x + threadIdx.x; t < P4; t += stride) {
        const float4* v4 = reinterpret_cast<const float4*>(vec) + 3ull * (unsigned)t;
        float4 A = v4[0], B = v4[1], C = v4[2];
        int4 id = reinterpret_cast<const int4*>(atom)[t];
        int s = (t * 4) / E_PAIRS;
        float* cs = coords + s * N_A;
        float px[4] = {A.x, A.w, B.z, C.y};
        float py[4] = {A.y, B.x, B.w, C.z};
        float pz[4] = {A.z, B.y, C.x, C.w};
        int ids[4]  = {id.x, id.y, id.z, id.w};
        #pragma unroll
        for (int j = 0; j < 4; ++j) {
            float d = sqrtf(px[j]*px[j] + py[j]*py[j] + pz[j]*pz[j]);
            float y = (d - 4.4f) / 1.1f;
            float z;
            if (y <= 0.0f)      z = 1.0f;
            else if (y >= 1.0f) z = 0.0f;
            else { float u = y - 1.0f; z = u * u * (1.0f + 2.0f * y); }
            if (z != 0.0f) unsafeAtomicAdd(&cs[ids[j]], z);
        }
    }
}

__global__ __launch_bounds__(256) void kde_reduce_f32(
    const float* __restrict__ coords, float* __restrict__ out)
{
    int s = blockIdx.y;
    int a = blockIdx.x * 256 + threadIdx.x;
    bool valid = (a < N_A);
    float c = valid ? coords[(size_t)s * N_A + a] : 0.0f;

    float vals[NBINS];
    #pragma unroll
    for (int k = 0; k < NBINS; ++k) {
        float d = c - (float)k;
        vals[k] = valid ? expf(-2.0f * d * d) : 0.0f;
    }
    #pragma unroll
    for (int k = 0; k < NBINS; ++k) {
        #pragma unroll
        for (int off = 32; off > 0; off >>= 1)
            vals[k] += __shfl_down(vals[k], off, 64);
    }
    __shared__ float sbin[4][NBINS];
    int wave = threadIdx.x >> 6;
    int lane = threadIdx.x & 63;
    if (lane == 0) {
        #pragma unroll
        for (int k = 0; k < NBINS; ++k) sbin[wave][k] = vals[k];
    }
    __syncthreads();
    if (threadIdx.x < NBINS) {
        float v = sbin[0][threadIdx.x] + sbin[1][threadIdx.x]
                + sbin[2][threadIdx.x] + sbin[3][threadIdx.x];
        unsafeAtomicAdd(&out[s * NBINS + threadIdx.x], v);
    }
}

extern "C" void kernel_launch(void* const* d_in, const int* in_sizes, int n_in,
                              void* d_out, int out_size, void* d_ws, size_t ws_size,
                              hipStream_t stream) {
    const float* vec  = (const float*)d_in[0];   // [S,E,3] f32
    const int*   atom = (const int*)d_in[1];     // [S,E] i32
    float* out = (float*)d_out;                  // [S,16] f32

    hipMemsetAsync(out, 0, (size_t)S_SYS * NBINS * sizeof(float), stream);

    const size_t need = (size_t)S_SYS * BPS * N_A * sizeof(unsigned);  // 20.5 MB
    dim3 g2((N_A + 255) / 256, S_SYS);

    if (ws_size >= need) {
        unsigned* ws = (unsigned*)d_ws;
        dim3 g1(BPS, S_SYS);                      // 256 blocks
        coord_lds_u32<<<g1, BLK, 0, stream>>>(vec, atom, ws);
        kde_reduce_u32<<<g2, 256, 0, stream>>>(ws, out);
    } else {
        float* ws = (float*)d_ws;
        hipMemsetAsync(ws, 0, (size_t)S_SYS * N_A * sizeof(float), stream);
        coord_scatter<<<2048, 256, 0, stream>>>(vec, atom, ws);
        kde_reduce_f32<<<g2, 256, 0, stream>>>(ws, out);
    }
}